// Round 2
// baseline (147.785 us; speedup 1.0000x reference)
//
#include <hip/hip_runtime.h>
#include <hip/hip_bf16.h>
#include <stdint.h>
#include <stddef.h>

// MDCT as folded GEMM, TWO-KERNEL structure (round-2 verified best) +
// XCD-swizzled gemm grid (round-5 verified: same-n blocks on one XCD).
//   out[512, 32784] = D[512,512] . V[512, 32784]
//   V[c][j] = j<256:  x[g+j] - x[g+511-j]
//             j>=256: x[g+j+256] + x[g+1279-j],   g = o*512 - 512 (per batch)
// Round-6 lessons: (a) fold fused into the GEMM's barrier-locked staging path
// costs more than a separate pass (register vmcnt wait serializes every
// k-iter); (b) BK=32 XOR swizzle only covers 4 bank-groups -> 4-way read
// conflicts. Reverted to BK=64 single-buffer gemm (0 conflicts, 41.5 us).
// Precision: single fp16 product; absmax 0.03125 vs threshold 0.1069.
// This session R1: XCD-swizzle fold_x grid (T1). Consecutive columns share
// half their 1024-float window; default dispatch puts them on different
// XCDs -> overlap re-fetched from HBM. 8224 blocks = 8*1028 exactly ->
// bijective swizzle gives each XCD a contiguous 4112-column range.
// Predict: fold_x FETCH ~128->~75 MB, fold_x dur -30..45%. gemm untouched.

constexpr int N_ = 512;
constexpr int T_ = 2048;
constexpr int B_ = 16;
constexpr int LEN = N_ * T_;              // 2^20 per batch
constexpr int FRAMES = T_ + 1;            // 2049
constexpr int COLS = B_ * FRAMES;         // 32784
constexpr int NT_TILES = 257;
constexpr int COLS_PAD = NT_TILES * 128;  // 32896
constexpr int KF = 512;
constexpr int BK = 64;

typedef __attribute__((ext_vector_type(8))) _Float16 f16x8;
typedef __attribute__((ext_vector_type(4))) _Float16 f16x4;
typedef __attribute__((ext_vector_type(4))) float f32x4;

#define GLD16(gptr, lptr)                                                     \
  __builtin_amdgcn_global_load_lds(                                           \
      (const __attribute__((address_space(1))) unsigned int*)(gptr),          \
      (__attribute__((address_space(3))) unsigned int*)(lptr), 16, 0, 0)

// ---------------- Kernel 1: gather filter -> fp16 D -------------------------
__global__ void prep_filter(const float* __restrict__ f,
                            _Float16* __restrict__ D) {
  int idx = (blockIdx.x * 256 + threadIdx.x) * 4;
  int k = idx >> 9;
  int j = idx & 511;
  int t = (j < 256) ? j : (j + 256);
  const float4 v = *(const float4*)&f[k * 1024 + t];
  f16x4 h = {(_Float16)v.x, (_Float16)v.y, (_Float16)v.z, (_Float16)v.w};
  *(f16x4*)&D[k * KF + j] = h;
}

// ---------------- Kernel 2: fold x -> V fp16, one wave per column -----------
// Lane l owns V[c][j0..j0+7]: l<32 -> j0=8l (minus half), l>=32 -> j0=256+8(l-32)
// (plus half). fwd stream ascending contiguous, rev stream descending
// contiguous; one f16x8 (16B) store -> wave writes the whole 1KB column.
// R1: block->column mapping XCD-swizzled: hw id b runs on XCD b&7; chunk
// (b>>3) walks a contiguous column range per XCD so overlapping windows
// (stride 512, size 1024) hit that XCD's L2 on the second read.
__global__ void fold_x(const float* __restrict__ x, _Float16* __restrict__ V) {
  const int blk = (blockIdx.x & 7) * 1028 + (blockIdx.x >> 3);  // bijective: 8224=8*1028
  const int c = blk * 4 + (threadIdx.x >> 6);  // 4 columns per block
  const int l = threadIdx.x & 63;
  const bool mi = (l < 32);
  const int j0 = mi ? (l * 8) : (256 + (l - 32) * 8);
  const float sgn = mi ? -1.0f : 1.0f;
  float4 a0 = {0.f, 0.f, 0.f, 0.f}, a1 = {0.f, 0.f, 0.f, 0.f};
  float4 r0 = {0.f, 0.f, 0.f, 0.f}, r1 = {0.f, 0.f, 0.f, 0.f};
  if (c < COLS) {
    int b = (int)((unsigned)c / (unsigned)FRAMES);
    int o = c - b * FRAMES;
    const int lo = b * LEN;
    const int g = lo + o * N_ - N_;            // absolute window start
    const int fb = g + (mi ? j0 : (j0 + 256)); // fwd segment (8 floats)
    const int rb = g + (mi ? (504 - j0) : (1272 - j0)); // rev segment
    // segments are 8-float aligned; batch bounds are multiples of 512
    // -> each 8-float segment is fully in or fully out (one predicate).
    if ((unsigned)(fb - lo) <= (unsigned)(LEN - 8)) {
      a0 = *(const float4*)(x + fb);
      a1 = *(const float4*)(x + fb + 4);
    }
    if ((unsigned)(rb - lo) <= (unsigned)(LEN - 8)) {
      r0 = *(const float4*)(x + rb);
      r1 = *(const float4*)(x + rb + 4);
    }
  }
  f16x8 h;
  h[0] = (_Float16)__builtin_fmaf(sgn, r1.w, a0.x);
  h[1] = (_Float16)__builtin_fmaf(sgn, r1.z, a0.y);
  h[2] = (_Float16)__builtin_fmaf(sgn, r1.y, a0.z);
  h[3] = (_Float16)__builtin_fmaf(sgn, r1.x, a0.w);
  h[4] = (_Float16)__builtin_fmaf(sgn, r0.w, a1.x);
  h[5] = (_Float16)__builtin_fmaf(sgn, r0.z, a1.y);
  h[6] = (_Float16)__builtin_fmaf(sgn, r0.y, a1.z);
  h[7] = (_Float16)__builtin_fmaf(sgn, r0.x, a1.w);
  if (c < COLS_PAD) *(f16x8*)&V[(size_t)c * KF + j0] = h;
}

// ---------------- Kernel 3: C = D . V, fp16 MFMA (round-2 verified) ---------
// 128x128 tile, BK=64 single-buffer, 4 waves (2x2 of 64x64), 16x16x32 f16.
// LDS slot = r*8 + (chunk ^ (r&7)) -> fragment reads 2-way aliased (free).
// Grid: 1056; id -> xcd=id&7, s=id>>3, m=s&3, nt=(s>>2)*8+xcd (r5 verified:
// FETCH 263->62 MB on the fused variant). Tail nt>=257 exits.
__global__ __launch_bounds__(256, 4) void gemm_fold(
    const _Float16* __restrict__ D, const _Float16* __restrict__ V,
    float* __restrict__ out) {
  __shared__ __align__(16) _Float16 As[128 * BK];
  __shared__ __align__(16) _Float16 Bs[128 * BK];

  const int id = blockIdx.x;
  const int xcd = id & 7;
  const int sb = id >> 3;
  const int nt = (sb >> 2) * 8 + xcd;
  if (nt >= NT_TILES) return;
  const int m0 = (sb & 3) * 128;
  const int n0 = nt * 128;

  const int tid = threadIdx.x;
  const int wid = tid >> 6;
  const int lane = tid & 63;
  const int quad = lane >> 4;
  const int l16 = lane & 15;
  const int mw = (wid >> 1) * 64;
  const int nw = (wid & 1) * 64;

  f32x4 acc[4][4];
#pragma unroll
  for (int i = 0; i < 4; ++i)
#pragma unroll
    for (int j = 0; j < 4; ++j) acc[i][j] = (f32x4){0.f, 0.f, 0.f, 0.f};

  for (int kt = 0; kt < KF / BK; ++kt) {  // 8 iterations
    const int kb = kt * BK;
    __syncthreads();  // previous tile fully consumed
#pragma unroll
    for (int it = 0; it < 4; ++it) {
      const int S = it * 256 + tid;          // LDS slot = uniform base + lane
      const int r = S >> 3;                  // tile row
      const int c = (S & 7) ^ (r & 7);       // swizzled global chunk
      const int goff = kb + c * 8;           // halves
      GLD16(D + (size_t)(m0 + r) * KF + goff, &As[S * 8]);
      GLD16(V + (size_t)(n0 + r) * KF + goff, &Bs[S * 8]);
    }
    __syncthreads();  // drains vmcnt: tiles ready

#pragma unroll
    for (int ko = 0; ko < 2; ++ko) {
      f16x8 af[4], bf[4];
#pragma unroll
      for (int i = 0; i < 4; ++i) {
        int ra = mw + i * 16 + l16;
        int rb = nw + i * 16 + l16;
        int ca = ko * 4 + quad;
        af[i] = *(const f16x8*)&As[(ra * 8 + (ca ^ (ra & 7))) * 8];
        bf[i] = *(const f16x8*)&Bs[(rb * 8 + (ca ^ (rb & 7))) * 8];
      }
#pragma unroll
      for (int i = 0; i < 4; ++i)
#pragma unroll
        for (int j = 0; j < 4; ++j)
          acc[i][j] = __builtin_amdgcn_mfma_f32_16x16x32_f16(af[i], bf[j], acc[i][j], 0, 0, 0);
    }
  }

  // Epilogue (verified r1-r6): C/D layout col = lane&15, row = quad*4 + reg.
#pragma unroll
  for (int i = 0; i < 4; ++i) {
#pragma unroll
    for (int j = 0; j < 4; ++j) {
      int col = n0 + nw + j * 16 + l16;
      if (col < COLS) {
        int b = col / FRAMES;
        int o = col - b * FRAMES;
        int rowb = m0 + mw + i * 16 + quad * 4;
        float* op = out + (size_t)b * N_ * FRAMES + (size_t)rowb * FRAMES + o;
#pragma unroll
        for (int r = 0; r < 4; ++r) op[(size_t)r * FRAMES] = acc[i][j][r];
      }
    }
  }
}

// ---------------- Fallback: direct fp32 conv (if ws too small) --------------
__global__ void naive_conv(const float* __restrict__ x, const float* __restrict__ f,
                           float* __restrict__ out) {
  int col = blockIdx.x;
  int k = threadIdx.x;
  __shared__ float win[1024];
  int b = col / FRAMES;
  int o = col - b * FRAMES;
  const float* xb = x + (size_t)b * LEN;
  int g = o * N_ - N_;
  for (int t = threadIdx.x; t < 1024; t += 512) {
    int i = g + t;
    win[t] = (i >= 0 && i < LEN) ? xb[i] : 0.0f;
  }
  __syncthreads();
  float s = 0.0f;
  const float* fk = f + (size_t)k * 1024;
  for (int t = 0; t < 1024; ++t) s += win[t] * fk[t];
  out[(size_t)b * N_ * FRAMES + (size_t)k * FRAMES + o] = s;
}

extern "C" void kernel_launch(void* const* d_in, const int* in_sizes, int n_in,
                              void* d_out, int out_size, void* d_ws, size_t ws_size,
                              hipStream_t stream) {
  const float* x = (const float*)d_in[0];
  const float* f = (const float*)d_in[1];
  float* out = (float*)d_out;

  const size_t elems_D = (size_t)512 * 512;
  const size_t elems_V = (size_t)COLS_PAD * KF;
  const size_t need = (elems_D + elems_V) * sizeof(_Float16);

  if (ws_size < need) {
    naive_conv<<<COLS, 512, 0, stream>>>(x, f, out);
    return;
  }

  _Float16* D = (_Float16*)d_ws;
  _Float16* V = D + elems_D;

  prep_filter<<<256, 256, 0, stream>>>(f, D);
  fold_x<<<COLS_PAD / 4, 256, 0, stream>>>(x, V);
  // Grid 1056 = 132*8: covers nt=0..256, m=0..3 (max id 1048); tail exits.
  gemm_fold<<<1056, 256, 0, stream>>>(D, V, out);
}

// Round 3
// 147.551 us; speedup vs baseline: 1.0016x; 1.0016x over previous
//
#include <hip/hip_runtime.h>
#include <hip/hip_bf16.h>
#include <stdint.h>
#include <stddef.h>

// MDCT as folded GEMM, TWO-KERNEL structure.
//   out[512, 32784] = D[512,512] . V[512, 32784]
//   V[c][j] = j<256:  x[g+j] - x[g+511-j]
//             j>=256: x[g+j+256] + x[g+1279-j],   g = o*512 - 512 (per batch)
// Precision: single fp16 product; absmax 0.03125 vs threshold 0.1069.
//
// R2 (this session): gemm counters showed MfmaUtil 13.7%, VALUBusy 9.1%,
// HBM 26% — stall-bound, not BW/compute-bound. Old loop had ZERO overlap:
// barrier -> stage -> barrier+drain -> MFMA, 8x. Convoyed blocks pay full
// load latency every iter. Fix = T3 minimum 2-phase: double-buffered LDS,
// STAGE(t+1) issued before compute(t), one barrier/iter. The end-of-iter
// drain now waits on loads that aged through ~600 cyc of MFMA+ds_read.
// LDS 32->64 KB (2 blocks/CU). Predict gemm 46.5 -> 30-35 us.

constexpr int N_ = 512;
constexpr int T_ = 2048;
constexpr int B_ = 16;
constexpr int LEN = N_ * T_;              // 2^20 per batch
constexpr int FRAMES = T_ + 1;            // 2049
constexpr int COLS = B_ * FRAMES;         // 32784
constexpr int NT_TILES = 257;
constexpr int COLS_PAD = NT_TILES * 128;  // 32896
constexpr int KF = 512;
constexpr int BK = 64;
constexpr int TILE_H = 128 * BK;          // elements per LDS buffer (8192)

typedef __attribute__((ext_vector_type(8))) _Float16 f16x8;
typedef __attribute__((ext_vector_type(4))) _Float16 f16x4;
typedef __attribute__((ext_vector_type(4))) float f32x4;

#define GLD16(gptr, lptr)                                                     \
  __builtin_amdgcn_global_load_lds(                                           \
      (const __attribute__((address_space(1))) unsigned int*)(gptr),          \
      (__attribute__((address_space(3))) unsigned int*)(lptr), 16, 0, 0)

// ---------------- Kernel 1: gather filter -> fp16 D -------------------------
__global__ void prep_filter(const float* __restrict__ f,
                            _Float16* __restrict__ D) {
  int idx = (blockIdx.x * 256 + threadIdx.x) * 4;
  int k = idx >> 9;
  int j = idx & 511;
  int t = (j < 256) ? j : (j + 256);
  const float4 v = *(const float4*)&f[k * 1024 + t];
  f16x4 h = {(_Float16)v.x, (_Float16)v.y, (_Float16)v.z, (_Float16)v.w};
  *(f16x4*)&D[k * KF + j] = h;
}

// ---------------- Kernel 2: fold x -> V fp16, one wave per column -----------
// Lane l owns V[c][j0..j0+7]: l<32 -> j0=8l (minus half), l>=32 -> j0=256+8(l-32)
// (plus half). fwd stream ascending contiguous, rev stream descending
// contiguous; one f16x8 (16B) store -> wave writes the whole 1KB column.
// R1: block->column mapping XCD-swizzled (bijective, 8224=8*1028) so
// overlapping windows hit the same XCD's L2.
__global__ void fold_x(const float* __restrict__ x, _Float16* __restrict__ V) {
  const int blk = (blockIdx.x & 7) * 1028 + (blockIdx.x >> 3);
  const int c = blk * 4 + (threadIdx.x >> 6);  // 4 columns per block
  const int l = threadIdx.x & 63;
  const bool mi = (l < 32);
  const int j0 = mi ? (l * 8) : (256 + (l - 32) * 8);
  const float sgn = mi ? -1.0f : 1.0f;
  float4 a0 = {0.f, 0.f, 0.f, 0.f}, a1 = {0.f, 0.f, 0.f, 0.f};
  float4 r0 = {0.f, 0.f, 0.f, 0.f}, r1 = {0.f, 0.f, 0.f, 0.f};
  if (c < COLS) {
    int b = (int)((unsigned)c / (unsigned)FRAMES);
    int o = c - b * FRAMES;
    const int lo = b * LEN;
    const int g = lo + o * N_ - N_;            // absolute window start
    const int fb = g + (mi ? j0 : (j0 + 256)); // fwd segment (8 floats)
    const int rb = g + (mi ? (504 - j0) : (1272 - j0)); // rev segment
    if ((unsigned)(fb - lo) <= (unsigned)(LEN - 8)) {
      a0 = *(const float4*)(x + fb);
      a1 = *(const float4*)(x + fb + 4);
    }
    if ((unsigned)(rb - lo) <= (unsigned)(LEN - 8)) {
      r0 = *(const float4*)(x + rb);
      r1 = *(const float4*)(x + rb + 4);
    }
  }
  f16x8 h;
  h[0] = (_Float16)__builtin_fmaf(sgn, r1.w, a0.x);
  h[1] = (_Float16)__builtin_fmaf(sgn, r1.z, a0.y);
  h[2] = (_Float16)__builtin_fmaf(sgn, r1.y, a0.z);
  h[3] = (_Float16)__builtin_fmaf(sgn, r1.x, a0.w);
  h[4] = (_Float16)__builtin_fmaf(sgn, r0.w, a1.x);
  h[5] = (_Float16)__builtin_fmaf(sgn, r0.z, a1.y);
  h[6] = (_Float16)__builtin_fmaf(sgn, r0.y, a1.z);
  h[7] = (_Float16)__builtin_fmaf(sgn, r0.x, a1.w);
  if (c < COLS_PAD) *(f16x8*)&V[(size_t)c * KF + j0] = h;
}

// ---------------- Kernel 3: C = D . V, fp16 MFMA ----------------------------
// 128x128 tile, BK=64 DOUBLE-buffer 2-phase, 4 waves (2x2 of 64x64),
// 16x16x32 f16. LDS slot = r*8 + (chunk ^ (r&7)) -> fragment reads 2-way
// aliased (free). Grid: 1056; id -> xcd=id&7, s=id>>3, m=s&3,
// nt=(s>>2)*8+xcd. Tail nt>=257 exits.
__global__ __launch_bounds__(256, 2) void gemm_fold(
    const _Float16* __restrict__ D, const _Float16* __restrict__ V,
    float* __restrict__ out) {
  __shared__ __align__(16) _Float16 As[2 * TILE_H];
  __shared__ __align__(16) _Float16 Bs[2 * TILE_H];

  const int id = blockIdx.x;
  const int xcd = id & 7;
  const int sb = id >> 3;
  const int nt = (sb >> 2) * 8 + xcd;
  if (nt >= NT_TILES) return;
  const int m0 = (sb & 3) * 128;
  const int n0 = nt * 128;

  const int tid = threadIdx.x;
  const int wid = tid >> 6;
  const int lane = tid & 63;
  const int quad = lane >> 4;
  const int l16 = lane & 15;
  const int mw = (wid >> 1) * 64;
  const int nw = (wid & 1) * 64;

  f32x4 acc[4][4];
#pragma unroll
  for (int i = 0; i < 4; ++i)
#pragma unroll
    for (int j = 0; j < 4; ++j) acc[i][j] = (f32x4){0.f, 0.f, 0.f, 0.f};

  // Stage K-tile kt into buffer buf (8 x 16B global_load_lds per thread).
  auto stage = [&](int buf, int kt) {
    const int kb = kt * BK;
    const int base = buf * TILE_H;
#pragma unroll
    for (int it = 0; it < 4; ++it) {
      const int S = it * 256 + tid;          // LDS slot = uniform base + lane
      const int r = S >> 3;                  // tile row
      const int c = (S & 7) ^ (r & 7);       // swizzled global chunk
      const int goff = kb + c * 8;           // halves
      GLD16(D + (size_t)(m0 + r) * KF + goff, &As[base + S * 8]);
      GLD16(V + (size_t)(n0 + r) * KF + goff, &Bs[base + S * 8]);
    }
  };

  // Prologue: fill buffer 0.
  stage(0, 0);
  asm volatile("s_waitcnt vmcnt(0)");
  __syncthreads();

  int cur = 0;
  for (int kt = 0; kt < KF / BK; ++kt) {  // 8 iterations
    // Issue next tile's loads into the other buffer BEFORE compute; their
    // latency hides under the 16 ds_read_b128 + 32 MFMA below.
    if (kt < KF / BK - 1) stage(cur ^ 1, kt + 1);

    const int base = cur * TILE_H;
#pragma unroll
    for (int ko = 0; ko < 2; ++ko) {
      f16x8 af[4], bf[4];
#pragma unroll
      for (int i = 0; i < 4; ++i) {
        int ra = mw + i * 16 + l16;
        int rb = nw + i * 16 + l16;
        int ca = ko * 4 + quad;
        af[i] = *(const f16x8*)&As[base + (ra * 8 + (ca ^ (ra & 7))) * 8];
        bf[i] = *(const f16x8*)&Bs[base + (rb * 8 + (ca ^ (rb & 7))) * 8];
      }
#pragma unroll
      for (int i = 0; i < 4; ++i)
#pragma unroll
        for (int j = 0; j < 4; ++j)
          acc[i][j] = __builtin_amdgcn_mfma_f32_16x16x32_f16(af[i], bf[j], acc[i][j], 0, 0, 0);
    }

    // Barrier (drains vmcnt+lgkmcnt): next buffer fully written, this
    // buffer fully consumed by all waves.
    __syncthreads();
    cur ^= 1;
  }

  // Epilogue (verified): C/D layout col = lane&15, row = quad*4 + reg.
#pragma unroll
  for (int i = 0; i < 4; ++i) {
#pragma unroll
    for (int j = 0; j < 4; ++j) {
      int col = n0 + nw + j * 16 + l16;
      if (col < COLS) {
        int b = col / FRAMES;
        int o = col - b * FRAMES;
        int rowb = m0 + mw + i * 16 + quad * 4;
        float* op = out + (size_t)b * N_ * FRAMES + (size_t)rowb * FRAMES + o;
#pragma unroll
        for (int r = 0; r < 4; ++r) op[(size_t)r * FRAMES] = acc[i][j][r];
      }
    }
  }
}

// ---------------- Fallback: direct fp32 conv (if ws too small) --------------
__global__ void naive_conv(const float* __restrict__ x, const float* __restrict__ f,
                           float* __restrict__ out) {
  int col = blockIdx.x;
  int k = threadIdx.x;
  __shared__ float win[1024];
  int b = col / FRAMES;
  int o = col - b * FRAMES;
  const float* xb = x + (size_t)b * LEN;
  int g = o * N_ - N_;
  for (int t = threadIdx.x; t < 1024; t += 512) {
    int i = g + t;
    win[t] = (i >= 0 && i < LEN) ? xb[i] : 0.0f;
  }
  __syncthreads();
  float s = 0.0f;
  const float* fk = f + (size_t)k * 1024;
  for (int t = 0; t < 1024; ++t) s += win[t] * fk[t];
  out[(size_t)b * N_ * FRAMES + (size_t)k * FRAMES + o] = s;
}

extern "C" void kernel_launch(void* const* d_in, const int* in_sizes, int n_in,
                              void* d_out, int out_size, void* d_ws, size_t ws_size,
                              hipStream_t stream) {
  const float* x = (const float*)d_in[0];
  const float* f = (const float*)d_in[1];
  float* out = (float*)d_out;

  const size_t elems_D = (size_t)512 * 512;
  const size_t elems_V = (size_t)COLS_PAD * KF;
  const size_t need = (elems_D + elems_V) * sizeof(_Float16);

  if (ws_size < need) {
    naive_conv<<<COLS, 512, 0, stream>>>(x, f, out);
    return;
  }

  _Float16* D = (_Float16*)d_ws;
  _Float16* V = D + elems_D;

  prep_filter<<<256, 256, 0, stream>>>(f, D);
  fold_x<<<COLS_PAD / 4, 256, 0, stream>>>(x, V);
  // Grid 1056 = 132*8: covers nt=0..256, m=0..3 (max id 1048); tail exits.
  gemm_fold<<<1056, 256, 0, stream>>>(D, V, out);
}

// Round 4
// 146.603 us; speedup vs baseline: 1.0081x; 1.0065x over previous
//
#include <hip/hip_runtime.h>
#include <hip/hip_bf16.h>
#include <stdint.h>
#include <stddef.h>

// MDCT as folded GEMM, TWO-KERNEL structure.
//   out[512, 32784] = D[512,512] . V[512, 32784]
//   V[c][j] = j<256:  x[g+j] - x[g+511-j]
//             j>=256: x[g+j+256] + x[g+1279-j],   g = o*512 - 512 (per batch)
// Precision: single fp16 product; absmax 0.03125 vs threshold 0.1069.
//
// R2 result: runtime-indexed dbuf gave NO MfmaUtil change (13.8%) — compiler
// can't disambiguate ds_read(buf cur) from global_load_lds(buf cur^1) when
// both index one array with runtime base -> inserts s_waitcnt vmcnt(0)
// BEFORE the ds_reads, serializing every k-iter (full load latency, zero
// overlap). R3 fix: STATIC double buffers (As0/Bs0/As1/Bs1 as distinct
// __shared__ objects, k-loop unrolled in pairs) so AA proves independence
// and the only vmcnt drain is at the barrier, after the prefetch aged
// through the whole compute phase. Predict MfmaUtil -> 22-30%, gemm ~30 us.

constexpr int N_ = 512;
constexpr int T_ = 2048;
constexpr int B_ = 16;
constexpr int LEN = N_ * T_;              // 2^20 per batch
constexpr int FRAMES = T_ + 1;            // 2049
constexpr int COLS = B_ * FRAMES;         // 32784
constexpr int NT_TILES = 257;
constexpr int COLS_PAD = NT_TILES * 128;  // 32896
constexpr int KF = 512;
constexpr int BK = 64;
constexpr int TILE_H = 128 * BK;          // elements per LDS buffer (8192)

typedef __attribute__((ext_vector_type(8))) _Float16 f16x8;
typedef __attribute__((ext_vector_type(4))) _Float16 f16x4;
typedef __attribute__((ext_vector_type(4))) float f32x4;

#define GLD16(gptr, lptr)                                                     \
  __builtin_amdgcn_global_load_lds(                                           \
      (const __attribute__((address_space(1))) unsigned int*)(gptr),          \
      (__attribute__((address_space(3))) unsigned int*)(lptr), 16, 0, 0)

// ---------------- Kernel 1: gather filter -> fp16 D -------------------------
__global__ void prep_filter(const float* __restrict__ f,
                            _Float16* __restrict__ D) {
  int idx = (blockIdx.x * 256 + threadIdx.x) * 4;
  int k = idx >> 9;
  int j = idx & 511;
  int t = (j < 256) ? j : (j + 256);
  const float4 v = *(const float4*)&f[k * 1024 + t];
  f16x4 h = {(_Float16)v.x, (_Float16)v.y, (_Float16)v.z, (_Float16)v.w};
  *(f16x4*)&D[k * KF + j] = h;
}

// ---------------- Kernel 2: fold x -> V fp16, one wave per column -----------
// Lane l owns V[c][j0..j0+7]: l<32 -> j0=8l (minus half), l>=32 -> j0=256+8(l-32)
// (plus half). fwd stream ascending contiguous, rev stream descending
// contiguous; one f16x8 (16B) store -> wave writes the whole 1KB column.
// R1: block->column mapping XCD-swizzled (bijective, 8224=8*1028) so
// overlapping windows hit the same XCD's L2.
__global__ void fold_x(const float* __restrict__ x, _Float16* __restrict__ V) {
  const int blk = (blockIdx.x & 7) * 1028 + (blockIdx.x >> 3);
  const int c = blk * 4 + (threadIdx.x >> 6);  // 4 columns per block
  const int l = threadIdx.x & 63;
  const bool mi = (l < 32);
  const int j0 = mi ? (l * 8) : (256 + (l - 32) * 8);
  const float sgn = mi ? -1.0f : 1.0f;
  float4 a0 = {0.f, 0.f, 0.f, 0.f}, a1 = {0.f, 0.f, 0.f, 0.f};
  float4 r0 = {0.f, 0.f, 0.f, 0.f}, r1 = {0.f, 0.f, 0.f, 0.f};
  if (c < COLS) {
    int b = (int)((unsigned)c / (unsigned)FRAMES);
    int o = c - b * FRAMES;
    const int lo = b * LEN;
    const int g = lo + o * N_ - N_;            // absolute window start
    const int fb = g + (mi ? j0 : (j0 + 256)); // fwd segment (8 floats)
    const int rb = g + (mi ? (504 - j0) : (1272 - j0)); // rev segment
    if ((unsigned)(fb - lo) <= (unsigned)(LEN - 8)) {
      a0 = *(const float4*)(x + fb);
      a1 = *(const float4*)(x + fb + 4);
    }
    if ((unsigned)(rb - lo) <= (unsigned)(LEN - 8)) {
      r0 = *(const float4*)(x + rb);
      r1 = *(const float4*)(x + rb + 4);
    }
  }
  f16x8 h;
  h[0] = (_Float16)__builtin_fmaf(sgn, r1.w, a0.x);
  h[1] = (_Float16)__builtin_fmaf(sgn, r1.z, a0.y);
  h[2] = (_Float16)__builtin_fmaf(sgn, r1.y, a0.z);
  h[3] = (_Float16)__builtin_fmaf(sgn, r1.x, a0.w);
  h[4] = (_Float16)__builtin_fmaf(sgn, r0.w, a1.x);
  h[5] = (_Float16)__builtin_fmaf(sgn, r0.z, a1.y);
  h[6] = (_Float16)__builtin_fmaf(sgn, r0.y, a1.z);
  h[7] = (_Float16)__builtin_fmaf(sgn, r0.x, a1.w);
  if (c < COLS_PAD) *(f16x8*)&V[(size_t)c * KF + j0] = h;
}

// ---------------- Kernel 3: C = D . V, fp16 MFMA ----------------------------
// 128x128 tile, BK=64 STATIC double-buffer 2-phase, 4 waves (2x2 of 64x64),
// 16x16x32 f16. LDS slot = r*8 + (chunk ^ (r&7)) -> fragment reads 2-way
// aliased (free). Grid: 1056; id -> xcd=id&7, s=id>>3, m=s&3,
// nt=(s>>2)*8+xcd. Tail nt>=257 exits.
__global__ __launch_bounds__(256, 2) void gemm_fold(
    const _Float16* __restrict__ D, const _Float16* __restrict__ V,
    float* __restrict__ out) {
  // Four DISTINCT shared objects: alias analysis must be able to prove
  // ds_read(As0) independent of global_load_lds writes to As1.
  __shared__ __align__(16) _Float16 As0[TILE_H];
  __shared__ __align__(16) _Float16 Bs0[TILE_H];
  __shared__ __align__(16) _Float16 As1[TILE_H];
  __shared__ __align__(16) _Float16 Bs1[TILE_H];

  const int id = blockIdx.x;
  const int xcd = id & 7;
  const int sb = id >> 3;
  const int nt = (sb >> 2) * 8 + xcd;
  if (nt >= NT_TILES) return;
  const int m0 = (sb & 3) * 128;
  const int n0 = nt * 128;

  const int tid = threadIdx.x;
  const int wid = tid >> 6;
  const int lane = tid & 63;
  const int quad = lane >> 4;
  const int l16 = lane & 15;
  const int mw = (wid >> 1) * 64;
  const int nw = (wid & 1) * 64;

  f32x4 acc[4][4];
#pragma unroll
  for (int i = 0; i < 4; ++i)
#pragma unroll
    for (int j = 0; j < 4; ++j) acc[i][j] = (f32x4){0.f, 0.f, 0.f, 0.f};

  // Stage K-tile KT into (AS,BS): 8 x 16B global_load_lds per thread.
#define STAGE(AS, BS, KT)                                                     \
  do {                                                                        \
    const int kb_ = (KT) * BK;                                                \
    _Pragma("unroll")                                                         \
    for (int it = 0; it < 4; ++it) {                                          \
      const int S_ = it * 256 + tid;   /* LDS slot = uniform base + lane */   \
      const int r_ = S_ >> 3;          /* tile row */                         \
      const int c_ = (S_ & 7) ^ (r_ & 7); /* swizzled global chunk */         \
      const int g_ = kb_ + c_ * 8;                                            \
      GLD16(D + (size_t)(m0 + r_) * KF + g_, &(AS)[S_ * 8]);                  \
      GLD16(V + (size_t)(n0 + r_) * KF + g_, &(BS)[S_ * 8]);                  \
    }                                                                         \
  } while (0)

  // 32 MFMA on (AS,BS).
#define COMPUTE(AS, BS)                                                       \
  do {                                                                        \
    _Pragma("unroll")                                                         \
    for (int ko = 0; ko < 2; ++ko) {                                          \
      f16x8 af[4], bf[4];                                                     \
      _Pragma("unroll")                                                       \
      for (int i = 0; i < 4; ++i) {                                           \
        int ra_ = mw + i * 16 + l16;                                          \
        int rb_ = nw + i * 16 + l16;                                          \
        int ca_ = ko * 4 + quad;                                              \
        af[i] = *(const f16x8*)&(AS)[(ra_ * 8 + (ca_ ^ (ra_ & 7))) * 8];      \
        bf[i] = *(const f16x8*)&(BS)[(rb_ * 8 + (ca_ ^ (rb_ & 7))) * 8];      \
      }                                                                       \
      _Pragma("unroll")                                                       \
      for (int i = 0; i < 4; ++i)                                             \
        _Pragma("unroll")                                                     \
        for (int j = 0; j < 4; ++j)                                           \
          acc[i][j] = __builtin_amdgcn_mfma_f32_16x16x32_f16(af[i], bf[j],    \
                                                             acc[i][j],      \
                                                             0, 0, 0);        \
    }                                                                         \
  } while (0)

  // Prologue: fill buffer 0.
  STAGE(As0, Bs0, 0);
  asm volatile("s_waitcnt vmcnt(0)");
  __syncthreads();

#pragma unroll
  for (int kp = 0; kp < 4; ++kp) {
    // Step A: prefetch tile 2kp+1 into buf1, compute from buf0.
    STAGE(As1, Bs1, kp * 2 + 1);
    COMPUTE(As0, Bs0);
    __syncthreads();  // drains vmcnt: buf1 ready; all waves done with buf0
    // Step B: prefetch tile 2kp+2 into buf0, compute from buf1.
    if (kp < 3) {
      STAGE(As0, Bs0, kp * 2 + 2);
      COMPUTE(As1, Bs1);
      __syncthreads();
    } else {
      COMPUTE(As1, Bs1);  // last tile, no prefetch, no barrier needed
    }
  }
#undef STAGE
#undef COMPUTE

  // Epilogue (verified): C/D layout col = lane&15, row = quad*4 + reg.
#pragma unroll
  for (int i = 0; i < 4; ++i) {
#pragma unroll
    for (int j = 0; j < 4; ++j) {
      int col = n0 + nw + j * 16 + l16;
      if (col < COLS) {
        int b = col / FRAMES;
        int o = col - b * FRAMES;
        int rowb = m0 + mw + i * 16 + quad * 4;
        float* op = out + (size_t)b * N_ * FRAMES + (size_t)rowb * FRAMES + o;
#pragma unroll
        for (int r = 0; r < 4; ++r) op[(size_t)r * FRAMES] = acc[i][j][r];
      }
    }
  }
}

// ---------------- Fallback: direct fp32 conv (if ws too small) --------------
__global__ void naive_conv(const float* __restrict__ x, const float* __restrict__ f,
                           float* __restrict__ out) {
  int col = blockIdx.x;
  int k = threadIdx.x;
  __shared__ float win[1024];
  int b = col / FRAMES;
  int o = col - b * FRAMES;
  const float* xb = x + (size_t)b * LEN;
  int g = o * N_ - N_;
  for (int t = threadIdx.x; t < 1024; t += 512) {
    int i = g + t;
    win[t] = (i >= 0 && i < LEN) ? xb[i] : 0.0f;
  }
  __syncthreads();
  float s = 0.0f;
  const float* fk = f + (size_t)k * 1024;
  for (int t = 0; t < 1024; ++t) s += win[t] * fk[t];
  out[(size_t)b * N_ * FRAMES + (size_t)k * FRAMES + o] = s;
}

extern "C" void kernel_launch(void* const* d_in, const int* in_sizes, int n_in,
                              void* d_out, int out_size, void* d_ws, size_t ws_size,
                              hipStream_t stream) {
  const float* x = (const float*)d_in[0];
  const float* f = (const float*)d_in[1];
  float* out = (float*)d_out;

  const size_t elems_D = (size_t)512 * 512;
  const size_t elems_V = (size_t)COLS_PAD * KF;
  const size_t need = (elems_D + elems_V) * sizeof(_Float16);

  if (ws_size < need) {
    naive_conv<<<COLS, 512, 0, stream>>>(x, f, out);
    return;
  }

  _Float16* D = (_Float16*)d_ws;
  _Float16* V = D + elems_D;

  prep_filter<<<256, 256, 0, stream>>>(f, D);
  fold_x<<<COLS_PAD / 4, 256, 0, stream>>>(x, V);
  // Grid 1056 = 132*8: covers nt=0..256, m=0..3 (max id 1048); tail exits.
  gemm_fold<<<1056, 256, 0, stream>>>(D, V, out);
}

// Round 5
// 145.520 us; speedup vs baseline: 1.0156x; 1.0074x over previous
//
#include <hip/hip_runtime.h>
#include <hip/hip_bf16.h>
#include <stdint.h>
#include <stddef.h>

// MDCT as folded GEMM, TWO-KERNEL structure.
//   out[512, 32784] = D[512,512] . V[512, 32784]
//   V[c][j] = j<256:  x[g+j] - x[g+511-j]
//             j>=256: x[g+j+256] + x[g+1279-j],   g = o*512 - 512 (per batch)
// Precision: single fp16 product; absmax 0.03125 vs threshold 0.1069.
//
// R4 (this session): R2/R3 dbuf attempts were NULL because the loop still
// ended in __syncthreads() == s_waitcnt vmcnt(0); s_barrier — vmcnt(0)
// waits for the prefetch issued ~400 cyc earlier, which needs ~1500-2000
// cyc to land => ~1100-1600 cyc stall/iter, MfmaUtil pinned at 14%.
// (Catalog m218: "8-phase-with-drain0 == 1-phase; T3's gain IS T4".)
// Fix: counted vmcnt + RAW s_barrier. Per iter: STAGE(next) [+8 vmem];
// s_waitcnt vmcnt(8)  -> waits only the OLDEST 8 (cur tile, aged one full
// iter, ~free); s_barrier -> collective "cur tile complete"; COMPUTE(cur);
// sched_barrier; s_barrier -> all waves done reading, safe to overwrite.
// The 8 newest loads stay in flight ACROSS both barriers.
// Predict: MfmaUtil -> 25-35%, gemm 44 -> 24-30 us.

constexpr int N_ = 512;
constexpr int T_ = 2048;
constexpr int B_ = 16;
constexpr int LEN = N_ * T_;              // 2^20 per batch
constexpr int FRAMES = T_ + 1;            // 2049
constexpr int COLS = B_ * FRAMES;         // 32784
constexpr int NT_TILES = 257;
constexpr int COLS_PAD = NT_TILES * 128;  // 32896
constexpr int KF = 512;
constexpr int BK = 64;
constexpr int TILE_H = 128 * BK;          // elements per LDS buffer (8192)

typedef __attribute__((ext_vector_type(8))) _Float16 f16x8;
typedef __attribute__((ext_vector_type(4))) _Float16 f16x4;
typedef __attribute__((ext_vector_type(4))) float f32x4;

#define GLD16(gptr, lptr)                                                     \
  __builtin_amdgcn_global_load_lds(                                           \
      (const __attribute__((address_space(1))) unsigned int*)(gptr),          \
      (__attribute__((address_space(3))) unsigned int*)(lptr), 16, 0, 0)

// ---------------- Kernel 1: gather filter -> fp16 D -------------------------
__global__ void prep_filter(const float* __restrict__ f,
                            _Float16* __restrict__ D) {
  int idx = (blockIdx.x * 256 + threadIdx.x) * 4;
  int k = idx >> 9;
  int j = idx & 511;
  int t = (j < 256) ? j : (j + 256);
  const float4 v = *(const float4*)&f[k * 1024 + t];
  f16x4 h = {(_Float16)v.x, (_Float16)v.y, (_Float16)v.z, (_Float16)v.w};
  *(f16x4*)&D[k * KF + j] = h;
}

// ---------------- Kernel 2: fold x -> V fp16, one wave per column -----------
// Lane l owns V[c][j0..j0+7]: l<32 -> j0=8l (minus half), l>=32 -> j0=256+8(l-32)
// (plus half). fwd stream ascending contiguous, rev stream descending
// contiguous; one f16x8 (16B) store -> wave writes the whole 1KB column.
// R1: block->column mapping XCD-swizzled (bijective, 8224=8*1028) so
// overlapping windows hit the same XCD's L2.
__global__ void fold_x(const float* __restrict__ x, _Float16* __restrict__ V) {
  const int blk = (blockIdx.x & 7) * 1028 + (blockIdx.x >> 3);
  const int c = blk * 4 + (threadIdx.x >> 6);  // 4 columns per block
  const int l = threadIdx.x & 63;
  const bool mi = (l < 32);
  const int j0 = mi ? (l * 8) : (256 + (l - 32) * 8);
  const float sgn = mi ? -1.0f : 1.0f;
  float4 a0 = {0.f, 0.f, 0.f, 0.f}, a1 = {0.f, 0.f, 0.f, 0.f};
  float4 r0 = {0.f, 0.f, 0.f, 0.f}, r1 = {0.f, 0.f, 0.f, 0.f};
  if (c < COLS) {
    int b = (int)((unsigned)c / (unsigned)FRAMES);
    int o = c - b * FRAMES;
    const int lo = b * LEN;
    const int g = lo + o * N_ - N_;            // absolute window start
    const int fb = g + (mi ? j0 : (j0 + 256)); // fwd segment (8 floats)
    const int rb = g + (mi ? (504 - j0) : (1272 - j0)); // rev segment
    if ((unsigned)(fb - lo) <= (unsigned)(LEN - 8)) {
      a0 = *(const float4*)(x + fb);
      a1 = *(const float4*)(x + fb + 4);
    }
    if ((unsigned)(rb - lo) <= (unsigned)(LEN - 8)) {
      r0 = *(const float4*)(x + rb);
      r1 = *(const float4*)(x + rb + 4);
    }
  }
  f16x8 h;
  h[0] = (_Float16)__builtin_fmaf(sgn, r1.w, a0.x);
  h[1] = (_Float16)__builtin_fmaf(sgn, r1.z, a0.y);
  h[2] = (_Float16)__builtin_fmaf(sgn, r1.y, a0.z);
  h[3] = (_Float16)__builtin_fmaf(sgn, r1.x, a0.w);
  h[4] = (_Float16)__builtin_fmaf(sgn, r0.w, a1.x);
  h[5] = (_Float16)__builtin_fmaf(sgn, r0.z, a1.y);
  h[6] = (_Float16)__builtin_fmaf(sgn, r0.y, a1.z);
  h[7] = (_Float16)__builtin_fmaf(sgn, r0.x, a1.w);
  if (c < COLS_PAD) *(f16x8*)&V[(size_t)c * KF + j0] = h;
}

// ---------------- Kernel 3: C = D . V, fp16 MFMA ----------------------------
// 128x128 tile, BK=64 static dbuf, COUNTED-vmcnt 2-phase, 4 waves (2x2 of
// 64x64), 16x16x32 f16. LDS slot = r*8 + (chunk ^ (r&7)) -> fragment reads
// 2-way aliased (free). Grid: 1056; id -> xcd=id&7, s=id>>3, m=s&3,
// nt=(s>>2)*8+xcd. Tail nt>=257 exits.
__global__ __launch_bounds__(256, 2) void gemm_fold(
    const _Float16* __restrict__ D, const _Float16* __restrict__ V,
    float* __restrict__ out) {
  __shared__ __align__(16) _Float16 As0[TILE_H];
  __shared__ __align__(16) _Float16 Bs0[TILE_H];
  __shared__ __align__(16) _Float16 As1[TILE_H];
  __shared__ __align__(16) _Float16 Bs1[TILE_H];

  const int id = blockIdx.x;
  const int xcd = id & 7;
  const int sb = id >> 3;
  const int nt = (sb >> 2) * 8 + xcd;
  if (nt >= NT_TILES) return;
  const int m0 = (sb & 3) * 128;
  const int n0 = nt * 128;

  const int tid = threadIdx.x;
  const int wid = tid >> 6;
  const int lane = tid & 63;
  const int quad = lane >> 4;
  const int l16 = lane & 15;
  const int mw = (wid >> 1) * 64;
  const int nw = (wid & 1) * 64;

  f32x4 acc[4][4];
#pragma unroll
  for (int i = 0; i < 4; ++i)
#pragma unroll
    for (int j = 0; j < 4; ++j) acc[i][j] = (f32x4){0.f, 0.f, 0.f, 0.f};

  // Stage K-tile KT into (AS,BS): 8 x 16B global_load_lds per thread.
#define STAGE(AS, BS, KT)                                                     \
  do {                                                                        \
    const int kb_ = (KT) * BK;                                                \
    _Pragma("unroll")                                                         \
    for (int it = 0; it < 4; ++it) {                                          \
      const int S_ = it * 256 + tid;   /* LDS slot = uniform base + lane */   \
      const int r_ = S_ >> 3;          /* tile row */                         \
      const int c_ = (S_ & 7) ^ (r_ & 7); /* swizzled global chunk */         \
      const int g_ = kb_ + c_ * 8;                                            \
      GLD16(D + (size_t)(m0 + r_) * KF + g_, &(AS)[S_ * 8]);                  \
      GLD16(V + (size_t)(n0 + r_) * KF + g_, &(BS)[S_ * 8]);                  \
    }                                                                         \
  } while (0)

  // 32 MFMA on (AS,BS).
#define COMPUTE(AS, BS)                                                       \
  do {                                                                        \
    _Pragma("unroll")                                                         \
    for (int ko = 0; ko < 2; ++ko) {                                          \
      f16x8 af[4], bf[4];                                                     \
      _Pragma("unroll")                                                       \
      for (int i = 0; i < 4; ++i) {                                           \
        int ra_ = mw + i * 16 + l16;                                          \
        int rb_ = nw + i * 16 + l16;                                          \
        int ca_ = ko * 4 + quad;                                              \
        af[i] = *(const f16x8*)&(AS)[(ra_ * 8 + (ca_ ^ (ra_ & 7))) * 8];      \
        bf[i] = *(const f16x8*)&(BS)[(rb_ * 8 + (ca_ ^ (rb_ & 7))) * 8];      \
      }                                                                       \
      _Pragma("unroll")                                                       \
      for (int i = 0; i < 4; ++i)                                             \
        _Pragma("unroll")                                                     \
        for (int j = 0; j < 4; ++j)                                           \
          acc[i][j] = __builtin_amdgcn_mfma_f32_16x16x32_f16(af[i], bf[j],    \
                                                             acc[i][j],      \
                                                             0, 0, 0);        \
    }                                                                         \
  } while (0)

  // Counted wait: leave the N newest VMEM ops in flight, drain the rest.
#define WAITV(N) asm volatile("s_waitcnt vmcnt(" #N ")" ::: "memory")
#define BAR() __builtin_amdgcn_s_barrier()
#define SCHED0() __builtin_amdgcn_sched_barrier(0)

  // Prologue: fill buffer 0 (tile 0). 8 VMEM in flight.
  STAGE(As0, Bs0, 0);

  // Iter kt: tile kt in buf[kt&1]; stage tile kt+1 into buf[(kt+1)&1].
  // WAITV(8) drains the oldest 8 (tile kt, aged one full iteration);
  // the 8 newest (tile kt+1) stay in flight across both barriers.
#define STEP(AScur, BScur, ASnxt, BSnxt, KT)                                  \
  do {                                                                        \
    if ((KT) < 7) {                                                           \
      STAGE(ASnxt, BSnxt, (KT) + 1);                                          \
      WAITV(8);                                                               \
    } else {                                                                  \
      WAITV(0);                                                               \
    }                                                                         \
    BAR();     /* collective: tile KT fully in LDS */                         \
    SCHED0();                                                                 \
    COMPUTE(AScur, BScur);                                                    \
    SCHED0();  /* keep ds_read+MFMA above the barrier */                      \
    BAR();     /* all waves done reading -> buffer reusable */                \
  } while (0)

  STEP(As0, Bs0, As1, Bs1, 0);
  STEP(As1, Bs1, As0, Bs0, 1);
  STEP(As0, Bs0, As1, Bs1, 2);
  STEP(As1, Bs1, As0, Bs0, 3);
  STEP(As0, Bs0, As1, Bs1, 4);
  STEP(As1, Bs1, As0, Bs0, 5);
  STEP(As0, Bs0, As1, Bs1, 6);
  STEP(As1, Bs1, As0, Bs0, 7);

#undef STEP
#undef STAGE
#undef COMPUTE
#undef WAITV
#undef BAR
#undef SCHED0

  // Epilogue (verified): C/D layout col = lane&15, row = quad*4 + reg.
#pragma unroll
  for (int i = 0; i < 4; ++i) {
#pragma unroll
    for (int j = 0; j < 4; ++j) {
      int col = n0 + nw + j * 16 + l16;
      if (col < COLS) {
        int b = col / FRAMES;
        int o = col - b * FRAMES;
        int rowb = m0 + mw + i * 16 + quad * 4;
        float* op = out + (size_t)b * N_ * FRAMES + (size_t)rowb * FRAMES + o;
#pragma unroll
        for (int r = 0; r < 4; ++r) op[(size_t)r * FRAMES] = acc[i][j][r];
      }
    }
  }
}

// ---------------- Fallback: direct fp32 conv (if ws too small) --------------
__global__ void naive_conv(const float* __restrict__ x, const float* __restrict__ f,
                           float* __restrict__ out) {
  int col = blockIdx.x;
  int k = threadIdx.x;
  __shared__ float win[1024];
  int b = col / FRAMES;
  int o = col - b * FRAMES;
  const float* xb = x + (size_t)b * LEN;
  int g = o * N_ - N_;
  for (int t = threadIdx.x; t < 1024; t += 512) {
    int i = g + t;
    win[t] = (i >= 0 && i < LEN) ? xb[i] : 0.0f;
  }
  __syncthreads();
  float s = 0.0f;
  const float* fk = f + (size_t)k * 1024;
  for (int t = 0; t < 1024; ++t) s += win[t] * fk[t];
  out[(size_t)b * N_ * FRAMES + (size_t)k * FRAMES + o] = s;
}

extern "C" void kernel_launch(void* const* d_in, const int* in_sizes, int n_in,
                              void* d_out, int out_size, void* d_ws, size_t ws_size,
                              hipStream_t stream) {
  const float* x = (const float*)d_in[0];
  const float* f = (const float*)d_in[1];
  float* out = (float*)d_out;

  const size_t elems_D = (size_t)512 * 512;
  const size_t elems_V = (size_t)COLS_PAD * KF;
  const size_t need = (elems_D + elems_V) * sizeof(_Float16);

  if (ws_size < need) {
    naive_conv<<<COLS, 512, 0, stream>>>(x, f, out);
    return;
  }

  _Float16* D = (_Float16*)d_ws;
  _Float16* V = D + elems_D;

  prep_filter<<<256, 256, 0, stream>>>(f, D);
  fold_x<<<COLS_PAD / 4, 256, 0, stream>>>(x, V);
  // Grid 1056 = 132*8: covers nt=0..256, m=0..3 (max id 1048); tail exits.
  gemm_fold<<<1056, 256, 0, stream>>>(D, V, out);
}